// Round 2
// baseline (330.839 us; speedup 1.0000x reference)
//
#include <hip/hip_runtime.h>
#include <hip/hip_bf16.h>

typedef __attribute__((ext_vector_type(8))) short bf16x8;
typedef __attribute__((ext_vector_type(4))) float f32x4;

__device__ __forceinline__ unsigned short f2bf(float f) {
    unsigned x = __float_as_uint(f);
    unsigned r = (x + 0x7FFF + ((x >> 16) & 1)) >> 16;   // RNE
    return (unsigned short)r;
}

__device__ __forceinline__ bf16x8 cvt8(const float* __restrict__ p) {
    bf16x8 r;
#pragma unroll
    for (int j = 0; j < 8; ++j) r[j] = (short)f2bf(p[j]);
    return r;
}

// ---------------- kernel 0: weight prep (bf16 transpose to n-major) -------------
__global__ void prep_k(const float* __restrict__ w1,
                       const float* __restrict__ w2,
                       unsigned short* __restrict__ w1t,
                       unsigned short* __restrict__ w2t) {
    int t = threadIdx.x;
    for (int i = t; i < 128 * 64; i += 256) {
        int k = i >> 6, n = i & 63;
        w1t[n * 128 + k] = f2bf(w1[i]);
    }
    for (int i = t; i < 64 * 64; i += 256) {
        int k = i >> 6, n = i & 63;
        w2t[n * 64 + k] = f2bf(w2[i]);
    }
}

// ---------------- kernel 1: per-edge MLP -> logits, MFMA 16x16x32 bf16 ----------
// One wave handles 16 edges. A-frag: A[m=lane&15][k=(lane>>4)*8+j].
// B-frag: B[k=(lane>>4)*8+j][n=lane&15] -> n-major W^T rows, contiguous.
// C/D: row m=(lane>>4)*4+r, col n=lane&15.
__launch_bounds__(256)
__global__ void logits_k(const int* __restrict__ nodes,
                         const int* __restrict__ neigh,
                         const int* __restrict__ segs,
                         const float* __restrict__ u2e,
                         const unsigned short* __restrict__ w1t,
                         const unsigned short* __restrict__ w2t,
                         const float* __restrict__ b1f, const float* __restrict__ b2f,
                         const float* __restrict__ w3f, const float* __restrict__ b3f,
                         float* __restrict__ logits, int E) {
    __shared__ __align__(16) unsigned short h1buf[4][16 * 72];  // 16 x (64+8 pad)
    const int wid = threadIdx.x >> 6;
    const int lane = threadIdx.x & 63;
    const int q = lane >> 4;
    const int m15 = lane & 15;
    const long base = ((long)blockIdx.x * 4 + wid) * 16;

    long ee0 = base + m15;
    int e = (int)(ee0 < E ? ee0 : (long)E - 1);
    int ni = neigh[e];
    int ctr = nodes[segs[e]];
    const float* eu = u2e + (long)ni * 64;
    const float* ur = u2e + (long)ctr * 64;

    bf16x8 a0 = cvt8(eu + q * 8);
    bf16x8 a1 = cvt8(eu + 32 + q * 8);
    bf16x8 a2 = cvt8(ur + q * 8);
    bf16x8 a3 = cvt8(ur + 32 + q * 8);

    // ---- layer 1: h1 = relu(x @ W1 + b1), K=128, N=64 (4 col-blocks of 16)
    f32x4 acc[4];
#pragma unroll
    for (int b = 0; b < 4; ++b) {
        float bv = b1f[b * 16 + m15];
        acc[b] = (f32x4){bv, bv, bv, bv};
        const bf16x8* wrow = (const bf16x8*)(w1t + (b * 16 + m15) * 128);
        acc[b] = __builtin_amdgcn_mfma_f32_16x16x32_bf16(a0, wrow[0 + q], acc[b], 0, 0, 0);
        acc[b] = __builtin_amdgcn_mfma_f32_16x16x32_bf16(a1, wrow[4 + q], acc[b], 0, 0, 0);
        acc[b] = __builtin_amdgcn_mfma_f32_16x16x32_bf16(a2, wrow[8 + q], acc[b], 0, 0, 0);
        acc[b] = __builtin_amdgcn_mfma_f32_16x16x32_bf16(a3, wrow[12 + q], acc[b], 0, 0, 0);
    }
    // C-layout -> LDS (A-layout staging for layer 2), relu + bf16
#pragma unroll
    for (int b = 0; b < 4; ++b) {
#pragma unroll
        for (int r = 0; r < 4; ++r) {
            float v = fmaxf(acc[b][r], 0.0f);
            h1buf[wid][(q * 4 + r) * 72 + b * 16 + m15] = f2bf(v);
        }
    }
    __syncthreads();

    // ---- layer 2: h2 = relu(h1 @ W2 + b2), K=64
    const unsigned short* hrow = &h1buf[wid][m15 * 72];
    bf16x8 h0 = *(const bf16x8*)(hrow + q * 8);
    bf16x8 h1 = *(const bf16x8*)(hrow + 32 + q * 8);

    f32x4 acc2[4];
#pragma unroll
    for (int b = 0; b < 4; ++b) {
        float bv = b2f[b * 16 + m15];
        acc2[b] = (f32x4){bv, bv, bv, bv};
        const bf16x8* wrow = (const bf16x8*)(w2t + (b * 16 + m15) * 64);
        acc2[b] = __builtin_amdgcn_mfma_f32_16x16x32_bf16(h0, wrow[0 + q], acc2[b], 0, 0, 0);
        acc2[b] = __builtin_amdgcn_mfma_f32_16x16x32_bf16(h1, wrow[4 + q], acc2[b], 0, 0, 0);
    }

    // ---- layer 3: logit[m] = b3 + sum_n relu(h2)[m][n] * w3[n]
    float b3v = b3f[0];
#pragma unroll
    for (int r = 0; r < 4; ++r) {
        float v = 0.0f;
#pragma unroll
        for (int b = 0; b < 4; ++b) v += fmaxf(acc2[b][r], 0.0f) * w3f[b * 16 + m15];
        v += __shfl_xor(v, 1);
        v += __shfl_xor(v, 2);
        v += __shfl_xor(v, 4);
        v += __shfl_xor(v, 8);
        long ee = base + q * 4 + r;
        if (m15 == r && ee < E) logits[ee] = v + b3v;
    }
}

// ---------------- kernel 2: per-node segment softmax + weighted aggregation ------
__launch_bounds__(256)
__global__ void agg_k(const int* __restrict__ segs,
                      const int* __restrict__ neigh,
                      const float* __restrict__ u2e,
                      const float* __restrict__ logits,
                      float* __restrict__ out, int N, int E) {
    const int wid = threadIdx.x >> 6;
    const int lane = threadIdx.x & 63;
    const int n = blockIdx.x * 4 + wid;
    if (n >= N) return;

    int lo, hi;
    {
        int l = 0, r = E;
        while (l < r) { int mid = (l + r) >> 1; if (segs[mid] < n) l = mid + 1; else r = mid; }
        lo = l;
        r = E;
        while (l < r) { int mid = (l + r) >> 1; if (segs[mid] < n + 1) l = mid + 1; else r = mid; }
        hi = l;
    }

    float m = -INFINITY;
    for (int e = lo + lane; e < hi; e += 64) m = fmaxf(m, logits[e]);
    m = fmaxf(m, __shfl_xor(m, 32));
    m = fmaxf(m, __shfl_xor(m, 16));
    m = fmaxf(m, __shfl_xor(m, 8));
    m = fmaxf(m, __shfl_xor(m, 4));
    m = fmaxf(m, __shfl_xor(m, 2));
    m = fmaxf(m, __shfl_xor(m, 1));

    float s = 0.0f;
    for (int e = lo + lane; e < hi; e += 64) s += __expf(logits[e] - m);
    s += __shfl_xor(s, 32);
    s += __shfl_xor(s, 16);
    s += __shfl_xor(s, 8);
    s += __shfl_xor(s, 4);
    s += __shfl_xor(s, 2);
    s += __shfl_xor(s, 1);
    float inv = 1.0f / fmaxf(s, 1e-9f);

    float acc = 0.0f;
    for (int e = lo; e < hi; ++e) {
        float att = __expf(logits[e] - m) * inv;
        float v = u2e[(long)neigh[e] * 64 + lane];
        acc = fmaf(att, v, acc);
    }
    out[(long)n * 64 + lane] = acc;
}

extern "C" void kernel_launch(void* const* d_in, const int* in_sizes, int n_in,
                              void* d_out, int out_size, void* d_ws, size_t ws_size,
                              hipStream_t stream) {
    const int* nodes = (const int*)d_in[0];
    const int* neigh = (const int*)d_in[1];
    const int* segs  = (const int*)d_in[2];
    const float* u2e = (const float*)d_in[3];
    const float* w1  = (const float*)d_in[4];
    const float* b1  = (const float*)d_in[5];
    const float* w2  = (const float*)d_in[6];
    const float* b2  = (const float*)d_in[7];
    const float* w3  = (const float*)d_in[8];
    const float* b3  = (const float*)d_in[9];
    const int N = in_sizes[0];
    const int E = in_sizes[1];

    char* ws = (char*)d_ws;
    float* logits = (float*)ws;
    size_t off = (((size_t)E * 4) + 255) & ~(size_t)255;
    unsigned short* w1t = (unsigned short*)(ws + off); off += 128 * 64 * 2;
    unsigned short* w2t = (unsigned short*)(ws + off); off += 64 * 64 * 2;

    float* out = (float*)d_out;

    prep_k<<<1, 256, 0, stream>>>(w1, w2, w1t, w2t);

    const int waves1 = (E + 15) / 16;
    const int blocks1 = (waves1 + 3) / 4;
    logits_k<<<blocks1, 256, 0, stream>>>(nodes, neigh, segs, u2e, w1t, w2t,
                                          b1, b2, w3, b3, logits, E);

    const int blocks2 = (N + 3) / 4;
    agg_k<<<blocks2, 256, 0, stream>>>(segs, neigh, u2e, logits, out, N, E);
}

// Round 3
// 282.209 us; speedup vs baseline: 1.1723x; 1.1723x over previous
//
#include <hip/hip_runtime.h>
#include <hip/hip_bf16.h>

typedef __attribute__((ext_vector_type(8))) short bf16x8;
typedef __attribute__((ext_vector_type(4))) float f32x4;

__device__ __forceinline__ float bf2f(unsigned u) {
    return __uint_as_float(u << 16);
}
__device__ __forceinline__ unsigned short f2bf(float f) {
    unsigned x = __float_as_uint(f);
    unsigned r = (x + 0x7FFF + ((x >> 16) & 1)) >> 16;   // RNE
    return (unsigned short)r;
}

__device__ __forceinline__ bf16x8 cvt8(const float* __restrict__ p) {
    bf16x8 r;
#pragma unroll
    for (int j = 0; j < 8; ++j) r[j] = (short)f2bf(p[j]);
    return r;
}

// ---------------- kernel 0a: weight prep (bf16 transpose to n-major) ------------
__global__ void prep_k(const float* __restrict__ w1,
                       const float* __restrict__ w2,
                       unsigned short* __restrict__ w1t,
                       unsigned short* __restrict__ w2t) {
    int t = threadIdx.x;
    for (int i = t; i < 128 * 64; i += 256) {
        int k = i >> 6, n = i & 63;
        w1t[n * 128 + k] = f2bf(w1[i]);
    }
    for (int i = t; i < 64 * 64; i += 256) {
        int k = i >> 6, n = i & 63;
        w2t[n * 64 + k] = f2bf(w2[i]);
    }
}

// ---------------- kernel 0b: u2e f32 -> bf16 (streaming, 8 elems/thread) --------
__global__ void convert_k(const float* __restrict__ src,
                          unsigned short* __restrict__ dst, long n8) {
    long t = (long)blockIdx.x * blockDim.x + threadIdx.x;
    if (t >= n8) return;
    const float* p = src + t * 8;
    bf16x8 v;
#pragma unroll
    for (int j = 0; j < 8; ++j) v[j] = (short)f2bf(p[j]);
    *(bf16x8*)(dst + t * 8) = v;
}

// ---------------- kernel 0c: segment offsets via parallel binary search ---------
__global__ void bounds_k(const int* __restrict__ segs, int* __restrict__ seg_off,
                         int N, int E) {
    int t = blockIdx.x * blockDim.x + threadIdx.x;
    if (t > N) return;
    int l = 0, r = E;
    while (l < r) { int mid = (l + r) >> 1; if (segs[mid] < t) l = mid + 1; else r = mid; }
    seg_off[t] = l;
}

// ---------------- kernel 1: per-edge MLP -> logits, MFMA 16x16x32 bf16 ----------
// One wave per 16 edges. A-frag: A[m=lane&15][k=(lane>>4)*8+j].
// B-frag: B[k=(lane>>4)*8+j][n=lane&15] from n-major W^T. C/D: row=(lane>>4)*4+r, col=lane&15.
template <bool USEBF>
__launch_bounds__(256)
__global__ void logits_k(const int* __restrict__ nodes,
                         const int* __restrict__ neigh,
                         const int* __restrict__ segs,
                         const float* __restrict__ u2e,
                         const unsigned short* __restrict__ u2ebf,
                         const unsigned short* __restrict__ w1t,
                         const unsigned short* __restrict__ w2t,
                         const float* __restrict__ b1f, const float* __restrict__ b2f,
                         const float* __restrict__ w3f, const float* __restrict__ b3f,
                         float* __restrict__ logits, int E) {
    __shared__ __align__(16) unsigned short h1buf[4][16 * 72];  // 16 x (64+8 pad)
    const int wid = threadIdx.x >> 6;
    const int lane = threadIdx.x & 63;
    const int q = lane >> 4;
    const int m15 = lane & 15;
    const long base = ((long)blockIdx.x * 4 + wid) * 16;

    long ee0 = base + m15;
    int e = (int)(ee0 < E ? ee0 : (long)E - 1);
    int ni = neigh[e];
    int ctr = nodes[segs[e]];

    bf16x8 a0, a1, a2, a3;
    if constexpr (USEBF) {
        const unsigned short* eu = u2ebf + (long)ni * 64;
        const unsigned short* ur = u2ebf + (long)ctr * 64;
        a0 = *(const bf16x8*)(eu + q * 8);
        a1 = *(const bf16x8*)(eu + 32 + q * 8);
        a2 = *(const bf16x8*)(ur + q * 8);
        a3 = *(const bf16x8*)(ur + 32 + q * 8);
    } else {
        const float* eu = u2e + (long)ni * 64;
        const float* ur = u2e + (long)ctr * 64;
        a0 = cvt8(eu + q * 8);
        a1 = cvt8(eu + 32 + q * 8);
        a2 = cvt8(ur + q * 8);
        a3 = cvt8(ur + 32 + q * 8);
    }

    // ---- layer 1: h1 = relu(x @ W1 + b1), K=128, N=64 (4 col-blocks of 16)
    f32x4 acc[4];
#pragma unroll
    for (int b = 0; b < 4; ++b) {
        float bv = b1f[b * 16 + m15];
        acc[b] = (f32x4){bv, bv, bv, bv};
        const bf16x8* wrow = (const bf16x8*)(w1t + (b * 16 + m15) * 128);
        acc[b] = __builtin_amdgcn_mfma_f32_16x16x32_bf16(a0, wrow[0 + q], acc[b], 0, 0, 0);
        acc[b] = __builtin_amdgcn_mfma_f32_16x16x32_bf16(a1, wrow[4 + q], acc[b], 0, 0, 0);
        acc[b] = __builtin_amdgcn_mfma_f32_16x16x32_bf16(a2, wrow[8 + q], acc[b], 0, 0, 0);
        acc[b] = __builtin_amdgcn_mfma_f32_16x16x32_bf16(a3, wrow[12 + q], acc[b], 0, 0, 0);
    }
#pragma unroll
    for (int b = 0; b < 4; ++b) {
#pragma unroll
        for (int r = 0; r < 4; ++r) {
            float v = fmaxf(acc[b][r], 0.0f);
            h1buf[wid][(q * 4 + r) * 72 + b * 16 + m15] = f2bf(v);
        }
    }
    __syncthreads();

    // ---- layer 2: h2 = relu(h1 @ W2 + b2), K=64
    const unsigned short* hrow = &h1buf[wid][m15 * 72];
    bf16x8 h0 = *(const bf16x8*)(hrow + q * 8);
    bf16x8 h1 = *(const bf16x8*)(hrow + 32 + q * 8);

    f32x4 acc2[4];
#pragma unroll
    for (int b = 0; b < 4; ++b) {
        float bv = b2f[b * 16 + m15];
        acc2[b] = (f32x4){bv, bv, bv, bv};
        const bf16x8* wrow = (const bf16x8*)(w2t + (b * 16 + m15) * 64);
        acc2[b] = __builtin_amdgcn_mfma_f32_16x16x32_bf16(h0, wrow[0 + q], acc2[b], 0, 0, 0);
        acc2[b] = __builtin_amdgcn_mfma_f32_16x16x32_bf16(h1, wrow[4 + q], acc2[b], 0, 0, 0);
    }

    // ---- layer 3: logit[m] = b3 + sum_n relu(h2)[m][n] * w3[n]
    float b3v = b3f[0];
#pragma unroll
    for (int r = 0; r < 4; ++r) {
        float v = 0.0f;
#pragma unroll
        for (int b = 0; b < 4; ++b) v += fmaxf(acc2[b][r], 0.0f) * w3f[b * 16 + m15];
        v += __shfl_xor(v, 1);
        v += __shfl_xor(v, 2);
        v += __shfl_xor(v, 4);
        v += __shfl_xor(v, 8);
        long ee = base + q * 4 + r;
        if (m15 == r && ee < E) logits[ee] = v + b3v;
    }
}

// ---------------- kernel 2: per-node segment softmax + weighted aggregation ------
// One block (4 waves) per node. Pass 3: wave w, half h -> edge slot w*2+h (8 slots);
// 32 lanes x float2 cover the 64 channels.
__launch_bounds__(256)
__global__ void agg_k(const int* __restrict__ seg_off,
                      const int* __restrict__ neigh,
                      const float* __restrict__ u2e,
                      const float* __restrict__ logits,
                      float* __restrict__ out, int N) {
    const int n = blockIdx.x;
    const int wid = threadIdx.x >> 6;
    const int lane = threadIdx.x & 63;
    const int lo = seg_off[n];
    const int hi = seg_off[n + 1];

    // per-wave (redundant) max + denom over the segment
    float m = -INFINITY;
    for (int e = lo + lane; e < hi; e += 64) m = fmaxf(m, logits[e]);
    m = fmaxf(m, __shfl_xor(m, 32));
    m = fmaxf(m, __shfl_xor(m, 16));
    m = fmaxf(m, __shfl_xor(m, 8));
    m = fmaxf(m, __shfl_xor(m, 4));
    m = fmaxf(m, __shfl_xor(m, 2));
    m = fmaxf(m, __shfl_xor(m, 1));

    float s = 0.0f;
    for (int e = lo + lane; e < hi; e += 64) s += __expf(logits[e] - m);
    s += __shfl_xor(s, 32);
    s += __shfl_xor(s, 16);
    s += __shfl_xor(s, 8);
    s += __shfl_xor(s, 4);
    s += __shfl_xor(s, 2);
    s += __shfl_xor(s, 1);
    const float inv = 1.0f / fmaxf(s, 1e-9f);

    // pass 3: 8 edge slots in flight
    const int slot = wid * 2 + (lane >> 5);
    const int c2 = lane & 31;            // channels 2*c2, 2*c2+1
    float ax = 0.0f, ay = 0.0f;
    for (int e = lo + slot; e < hi; e += 8) {
        float att = __expf(logits[e] - m) * inv;
        const float* row = u2e + (long)neigh[e] * 64 + c2 * 2;
        float2 v = *(const float2*)row;
        ax = fmaf(att, v.x, ax);
        ay = fmaf(att, v.y, ay);
    }
    // fold halves: lanes 0-31 pick up lanes 32-63
    ax += __shfl_xor(ax, 32);
    ay += __shfl_xor(ay, 32);

    __shared__ float part[4][64];
    if (lane < 32) {
        part[wid][c2 * 2] = ax;
        part[wid][c2 * 2 + 1] = ay;
    }
    __syncthreads();
    int t = threadIdx.x;
    if (t < 64)
        out[(long)n * 64 + t] = part[0][t] + part[1][t] + part[2][t] + part[3][t];
}

extern "C" void kernel_launch(void* const* d_in, const int* in_sizes, int n_in,
                              void* d_out, int out_size, void* d_ws, size_t ws_size,
                              hipStream_t stream) {
    const int* nodes = (const int*)d_in[0];
    const int* neigh = (const int*)d_in[1];
    const int* segs  = (const int*)d_in[2];
    const float* u2e = (const float*)d_in[3];
    const float* w1  = (const float*)d_in[4];
    const float* b1  = (const float*)d_in[5];
    const float* w2  = (const float*)d_in[6];
    const float* b2  = (const float*)d_in[7];
    const float* w3  = (const float*)d_in[8];
    const float* b3  = (const float*)d_in[9];
    const int N = in_sizes[0];
    const int E = in_sizes[1];
    const long VD = in_sizes[3];          // V*64 elements of u2e

    char* ws = (char*)d_ws;
    size_t off = 0;
    auto alloc = [&](size_t bytes) { char* p = ws + off; off = (off + bytes + 255) & ~(size_t)255; return p; };
    float* logits = (float*)alloc((size_t)E * 4);
    int* seg_off = (int*)alloc((size_t)(N + 1) * 4);
    unsigned short* w1t = (unsigned short*)alloc(128 * 64 * 2);
    unsigned short* w2t = (unsigned short*)alloc(64 * 64 * 2);
    size_t base_need = off;
    unsigned short* u2ebf = (unsigned short*)(ws + base_need);
    const bool bfPath = (ws_size >= base_need + (size_t)VD * 2);

    float* out = (float*)d_out;

    prep_k<<<1, 256, 0, stream>>>(w1, w2, w1t, w2t);
    bounds_k<<<(N + 256) / 256, 256, 0, stream>>>(segs, seg_off, N, E);

    const int waves1 = (E + 15) / 16;
    const int blocks1 = (waves1 + 3) / 4;
    if (bfPath) {
        long n8 = VD / 8;
        convert_k<<<(int)((n8 + 255) / 256), 256, 0, stream>>>(u2e, u2ebf, n8);
        logits_k<true><<<blocks1, 256, 0, stream>>>(nodes, neigh, segs, u2e, u2ebf,
                                                    w1t, w2t, b1, b2, w3, b3, logits, E);
    } else {
        logits_k<false><<<blocks1, 256, 0, stream>>>(nodes, neigh, segs, u2e, nullptr,
                                                     w1t, w2t, b1, b2, w3, b3, logits, E);
    }

    agg_k<<<N, 256, 0, stream>>>(seg_off, neigh, u2e, logits, out, N);
}

// Round 4
// 242.979 us; speedup vs baseline: 1.3616x; 1.1615x over previous
//
#include <hip/hip_runtime.h>
#include <hip/hip_bf16.h>

typedef __attribute__((ext_vector_type(8))) short bf16x8;
typedef __attribute__((ext_vector_type(4))) float f32x4;

__device__ __forceinline__ unsigned short f2bf(float f) {
    unsigned x = __float_as_uint(f);
    unsigned r = (x + 0x7FFF + ((x >> 16) & 1)) >> 16;   // RNE
    return (unsigned short)r;
}

__device__ __forceinline__ bf16x8 cvt8(const float* __restrict__ p) {
    bf16x8 r;
#pragma unroll
    for (int j = 0; j < 8; ++j) r[j] = (short)f2bf(p[j]);
    return r;
}

// ---------------- kernel 0a: weight prep (bf16 transpose to n-major) ------------
__global__ void prep_k(const float* __restrict__ w1,
                       const float* __restrict__ w2,
                       unsigned short* __restrict__ w1t,
                       unsigned short* __restrict__ w2t) {
    int t = threadIdx.x;
    for (int i = t; i < 128 * 64; i += 256) {
        int k = i >> 6, n = i & 63;
        w1t[n * 128 + k] = f2bf(w1[i]);
    }
    for (int i = t; i < 64 * 64; i += 256) {
        int k = i >> 6, n = i & 63;
        w2t[n * 64 + k] = f2bf(w2[i]);
    }
}

// ---------------- kernel 0b: u2e f32 -> bf16 (streaming) ------------------------
__global__ void convert_k(const float* __restrict__ src,
                          unsigned short* __restrict__ dst, long n8) {
    long t = (long)blockIdx.x * blockDim.x + threadIdx.x;
    if (t >= n8) return;
    const float* p = src + t * 8;
    bf16x8 v;
#pragma unroll
    for (int j = 0; j < 8; ++j) v[j] = (short)f2bf(p[j]);
    *(bf16x8*)(dst + t * 8) = v;
}

// ---------------- kernel 0c: segment offsets via parallel binary search ---------
__global__ void bounds_k(const int* __restrict__ segs, int* __restrict__ seg_off,
                         int N, int E) {
    int t = blockIdx.x * blockDim.x + threadIdx.x;
    if (t > N) return;
    int l = 0, r = E;
    while (l < r) { int mid = (l + r) >> 1; if (segs[mid] < t) l = mid + 1; else r = mid; }
    seg_off[t] = l;
}

// ---------------- kernel 0d: per-node z = u2e[nodes] @ W1_bot + b1 (f32 out) ----
// One wave per 16 nodes; same MFMA frame as logits layer 1 but K=64 (W1 rows 64..127).
__launch_bounds__(256)
__global__ void z_k(const int* __restrict__ nodes,
                    const unsigned short* __restrict__ u2ebf,
                    const unsigned short* __restrict__ w1t,
                    const float* __restrict__ b1f,
                    float* __restrict__ z, int N) {
    const int wid = threadIdx.x >> 6;
    const int lane = threadIdx.x & 63;
    const int q = lane >> 4;
    const int m15 = lane & 15;
    const int wbase = (blockIdx.x * 4 + wid) * 16;
    if (wbase >= N) return;

    int nd = nodes[min(wbase + m15, N - 1)];
    const unsigned short* ur = u2ebf + (long)nd * 64;
    bf16x8 a0 = *(const bf16x8*)(ur + q * 8);
    bf16x8 a1 = *(const bf16x8*)(ur + 32 + q * 8);

    f32x4 acc[4];
#pragma unroll
    for (int b = 0; b < 4; ++b) {
        float bv = b1f[b * 16 + m15];
        acc[b] = (f32x4){bv, bv, bv, bv};
        const bf16x8* wrow = (const bf16x8*)(w1t + (b * 16 + m15) * 128);
        acc[b] = __builtin_amdgcn_mfma_f32_16x16x32_bf16(a0, wrow[8 + q], acc[b], 0, 0, 0);
        acc[b] = __builtin_amdgcn_mfma_f32_16x16x32_bf16(a1, wrow[12 + q], acc[b], 0, 0, 0);
    }
#pragma unroll
    for (int b = 0; b < 4; ++b)
#pragma unroll
        for (int r = 0; r < 4; ++r) {
            int row = wbase + q * 4 + r;
            if (row < N) z[(long)row * 64 + b * 16 + m15] = acc[b][r];
        }
}

// ---------------- kernel 1: per-edge MLP -> logits --------------------------------
// One wave per 16 edges. Layer 1: acc init from z[seg[e]] (u_rep half precomputed),
// only e_u half runs per edge (K=64, 2 k-steps).
__launch_bounds__(256)
__global__ void logits_k(const int* __restrict__ neigh,
                         const int* __restrict__ segs,
                         const unsigned short* __restrict__ u2ebf,
                         const float* __restrict__ z,
                         const unsigned short* __restrict__ w1t,
                         const unsigned short* __restrict__ w2t,
                         const float* __restrict__ b2f,
                         const float* __restrict__ w3f, const float* __restrict__ b3f,
                         float* __restrict__ logits, int E) {
    __shared__ __align__(16) unsigned short h1buf[4][16 * 72];  // per-wave slice
    const int wid = threadIdx.x >> 6;
    const int lane = threadIdx.x & 63;
    const int q = lane >> 4;
    const int m15 = lane & 15;
    const long base = ((long)blockIdx.x * 4 + wid) * 16;

    long ee0 = base + m15;
    int e = (int)(ee0 < E ? ee0 : (long)E - 1);
    int ni = neigh[e];
    const unsigned short* eu = u2ebf + (long)ni * 64;
    bf16x8 a0 = *(const bf16x8*)(eu + q * 8);
    bf16x8 a1 = *(const bf16x8*)(eu + 32 + q * 8);

    // seg row per accumulator row (rows q*4+r)
    int srow[4];
#pragma unroll
    for (int r = 0; r < 4; ++r) {
        long er = base + q * 4 + r;
        srow[r] = segs[(int)(er < E ? er : (long)E - 1)];
    }

    // ---- layer 1: acc = z[seg] + e_u @ W1_top
    f32x4 acc[4];
#pragma unroll
    for (int b = 0; b < 4; ++b) {
#pragma unroll
        for (int r = 0; r < 4; ++r) acc[b][r] = z[(long)srow[r] * 64 + b * 16 + m15];
        const bf16x8* wrow = (const bf16x8*)(w1t + (b * 16 + m15) * 128);
        acc[b] = __builtin_amdgcn_mfma_f32_16x16x32_bf16(a0, wrow[0 + q], acc[b], 0, 0, 0);
        acc[b] = __builtin_amdgcn_mfma_f32_16x16x32_bf16(a1, wrow[4 + q], acc[b], 0, 0, 0);
    }
#pragma unroll
    for (int b = 0; b < 4; ++b)
#pragma unroll
        for (int r = 0; r < 4; ++r) {
            float v = fmaxf(acc[b][r], 0.0f);
            h1buf[wid][(q * 4 + r) * 72 + b * 16 + m15] = f2bf(v);
        }
    // no __syncthreads: each wave reads only its own h1buf slice

    // ---- layer 2: h2 = relu(h1 @ W2 + b2), K=64
    const unsigned short* hrow = &h1buf[wid][m15 * 72];
    bf16x8 h0 = *(const bf16x8*)(hrow + q * 8);
    bf16x8 h1 = *(const bf16x8*)(hrow + 32 + q * 8);

    f32x4 acc2[4];
#pragma unroll
    for (int b = 0; b < 4; ++b) {
        float bv = b2f[b * 16 + m15];
        acc2[b] = (f32x4){bv, bv, bv, bv};
        const bf16x8* wrow = (const bf16x8*)(w2t + (b * 16 + m15) * 64);
        acc2[b] = __builtin_amdgcn_mfma_f32_16x16x32_bf16(h0, wrow[0 + q], acc2[b], 0, 0, 0);
        acc2[b] = __builtin_amdgcn_mfma_f32_16x16x32_bf16(h1, wrow[4 + q], acc2[b], 0, 0, 0);
    }

    // ---- layer 3
    float b3v = b3f[0];
#pragma unroll
    for (int r = 0; r < 4; ++r) {
        float v = 0.0f;
#pragma unroll
        for (int b = 0; b < 4; ++b) v += fmaxf(acc2[b][r], 0.0f) * w3f[b * 16 + m15];
        v += __shfl_xor(v, 1);
        v += __shfl_xor(v, 2);
        v += __shfl_xor(v, 4);
        v += __shfl_xor(v, 8);
        long ee = base + q * 4 + r;
        if (m15 == r && ee < E) logits[ee] = v + b3v;
    }
}

// ---------------- kernel 2: segment softmax + weighted aggregation ---------------
// One block per node. Chunked: stage exp(l-m) and neigh idx in LDS, accumulate
// UNNORMALIZED weighted sum (8 edge slots x 32 lanes x 2 ch), scale by 1/sum at end.
__launch_bounds__(256)
__global__ void agg_k(const int* __restrict__ seg_off,
                      const int* __restrict__ neigh,
                      const unsigned short* __restrict__ u2ebf,
                      const float* __restrict__ logits,
                      float* __restrict__ out, int N) {
    __shared__ float attL[256];
    __shared__ int idxL[256];
    __shared__ float part[4][64];
    __shared__ float redbuf[4];

    const int n = blockIdx.x;
    const int t = threadIdx.x;
    const int wid = t >> 6;
    const int lane = t & 63;
    const int lo = seg_off[n];
    const int hi = seg_off[n + 1];

    // ---- block max of logits over [lo,hi)
    float m = -INFINITY;
    for (int e = lo + t; e < hi; e += 256) m = fmaxf(m, logits[e]);
    m = fmaxf(m, __shfl_xor(m, 32));
    m = fmaxf(m, __shfl_xor(m, 16));
    m = fmaxf(m, __shfl_xor(m, 8));
    m = fmaxf(m, __shfl_xor(m, 4));
    m = fmaxf(m, __shfl_xor(m, 2));
    m = fmaxf(m, __shfl_xor(m, 1));
    if (lane == 0) redbuf[wid] = m;
    __syncthreads();
    m = fmaxf(fmaxf(redbuf[0], redbuf[1]), fmaxf(redbuf[2], redbuf[3]));

    const int slot = wid * 2 + (lane >> 5);
    const int c2 = lane & 31;
    float ax = 0.0f, ay = 0.0f, s = 0.0f;

    for (int cs = lo; cs < hi; cs += 256) {
        const int clen = min(256, hi - cs);
        if (t < clen) {
            float ex = __expf(logits[cs + t] - m);
            attL[t] = ex;
            idxL[t] = neigh[cs + t];
            s += ex;
        }
        __syncthreads();
        for (int j = slot; j < clen; j += 8) {
            float a = attL[j];
            unsigned v = *(const unsigned*)(u2ebf + (long)idxL[j] * 64 + c2 * 2);
            ax = fmaf(a, __uint_as_float(v << 16), ax);
            ay = fmaf(a, __uint_as_float(v & 0xFFFF0000u), ay);
        }
        __syncthreads();
    }

    // fold halves (lanes 0-31 collect), stash partials
    ax += __shfl_xor(ax, 32);
    ay += __shfl_xor(ay, 32);
    if (lane < 32) {
        part[wid][c2 * 2] = ax;
        part[wid][c2 * 2 + 1] = ay;
    }
    // sum of exp: wave reduce then LDS
    s += __shfl_xor(s, 32);
    s += __shfl_xor(s, 16);
    s += __shfl_xor(s, 8);
    s += __shfl_xor(s, 4);
    s += __shfl_xor(s, 2);
    s += __shfl_xor(s, 1);
    if (lane == 0) redbuf[wid] = s;
    __syncthreads();
    if (t < 64) {
        float stot = redbuf[0] + redbuf[1] + redbuf[2] + redbuf[3];
        float inv = 1.0f / fmaxf(stot, 1e-9f);
        out[(long)n * 64 + t] =
            (part[0][t] + part[1][t] + part[2][t] + part[3][t]) * inv;
    }
}

// ---------------- fallback (no-z / f32) variants kept minimal --------------------
__launch_bounds__(256)
__global__ void logits_fb_k(const int* __restrict__ nodes,
                            const int* __restrict__ neigh,
                            const int* __restrict__ segs,
                            const float* __restrict__ u2e,
                            const unsigned short* __restrict__ w1t,
                            const unsigned short* __restrict__ w2t,
                            const float* __restrict__ b1f, const float* __restrict__ b2f,
                            const float* __restrict__ w3f, const float* __restrict__ b3f,
                            float* __restrict__ logits, int E) {
    __shared__ __align__(16) unsigned short h1buf[4][16 * 72];
    const int wid = threadIdx.x >> 6;
    const int lane = threadIdx.x & 63;
    const int q = lane >> 4;
    const int m15 = lane & 15;
    const long base = ((long)blockIdx.x * 4 + wid) * 16;
    long ee0 = base + m15;
    int e = (int)(ee0 < E ? ee0 : (long)E - 1);
    int ni = neigh[e];
    int ctr = nodes[segs[e]];
    const float* eu = u2e + (long)ni * 64;
    const float* ur = u2e + (long)ctr * 64;
    bf16x8 a0 = cvt8(eu + q * 8), a1 = cvt8(eu + 32 + q * 8);
    bf16x8 a2 = cvt8(ur + q * 8), a3 = cvt8(ur + 32 + q * 8);
    f32x4 acc[4];
#pragma unroll
    for (int b = 0; b < 4; ++b) {
        float bv = b1f[b * 16 + m15];
        acc[b] = (f32x4){bv, bv, bv, bv};
        const bf16x8* wrow = (const bf16x8*)(w1t + (b * 16 + m15) * 128);
        acc[b] = __builtin_amdgcn_mfma_f32_16x16x32_bf16(a0, wrow[0 + q], acc[b], 0, 0, 0);
        acc[b] = __builtin_amdgcn_mfma_f32_16x16x32_bf16(a1, wrow[4 + q], acc[b], 0, 0, 0);
        acc[b] = __builtin_amdgcn_mfma_f32_16x16x32_bf16(a2, wrow[8 + q], acc[b], 0, 0, 0);
        acc[b] = __builtin_amdgcn_mfma_f32_16x16x32_bf16(a3, wrow[12 + q], acc[b], 0, 0, 0);
    }
#pragma unroll
    for (int b = 0; b < 4; ++b)
#pragma unroll
        for (int r = 0; r < 4; ++r)
            h1buf[wid][(q * 4 + r) * 72 + b * 16 + m15] = f2bf(fmaxf(acc[b][r], 0.0f));
    const unsigned short* hrow = &h1buf[wid][m15 * 72];
    bf16x8 h0 = *(const bf16x8*)(hrow + q * 8);
    bf16x8 h1 = *(const bf16x8*)(hrow + 32 + q * 8);
    f32x4 acc2[4];
#pragma unroll
    for (int b = 0; b < 4; ++b) {
        float bv = b2f[b * 16 + m15];
        acc2[b] = (f32x4){bv, bv, bv, bv};
        const bf16x8* wrow = (const bf16x8*)(w2t + (b * 16 + m15) * 64);
        acc2[b] = __builtin_amdgcn_mfma_f32_16x16x32_bf16(h0, wrow[0 + q], acc2[b], 0, 0, 0);
        acc2[b] = __builtin_amdgcn_mfma_f32_16x16x32_bf16(h1, wrow[4 + q], acc2[b], 0, 0, 0);
    }
    float b3v = b3f[0];
#pragma unroll
    for (int r = 0; r < 4; ++r) {
        float v = 0.0f;
#pragma unroll
        for (int b = 0; b < 4; ++b) v += fmaxf(acc2[b][r], 0.0f) * w3f[b * 16 + m15];
        v += __shfl_xor(v, 1);
        v += __shfl_xor(v, 2);
        v += __shfl_xor(v, 4);
        v += __shfl_xor(v, 8);
        long ee = base + q * 4 + r;
        if (m15 == r && ee < E) logits[ee] = v + b3v;
    }
}

__launch_bounds__(256)
__global__ void agg_fb_k(const int* __restrict__ seg_off,
                         const int* __restrict__ neigh,
                         const float* __restrict__ u2e,
                         const float* __restrict__ logits,
                         float* __restrict__ out, int N) {
    const int n = blockIdx.x;
    const int wid = threadIdx.x >> 6;
    const int lane = threadIdx.x & 63;
    const int lo = seg_off[n], hi = seg_off[n + 1];
    float m = -INFINITY;
    for (int e = lo + lane; e < hi; e += 64) m = fmaxf(m, logits[e]);
    for (int d = 32; d; d >>= 1) m = fmaxf(m, __shfl_xor(m, d));
    float s = 0.0f;
    for (int e = lo + lane; e < hi; e += 64) s += __expf(logits[e] - m);
    for (int d = 32; d; d >>= 1) s += __shfl_xor(s, d);
    float inv = 1.0f / fmaxf(s, 1e-9f);
    const int slot = wid * 2 + (lane >> 5);
    const int c2 = lane & 31;
    float ax = 0.0f, ay = 0.0f;
    for (int e = lo + slot; e < hi; e += 8) {
        float att = __expf(logits[e] - m) * inv;
        float2 v = *(const float2*)(u2e + (long)neigh[e] * 64 + c2 * 2);
        ax = fmaf(att, v.x, ax);
        ay = fmaf(att, v.y, ay);
    }
    ax += __shfl_xor(ax, 32);
    ay += __shfl_xor(ay, 32);
    __shared__ float part[4][64];
    if (lane < 32) { part[wid][c2 * 2] = ax; part[wid][c2 * 2 + 1] = ay; }
    __syncthreads();
    int t = threadIdx.x;
    if (t < 64) out[(long)n * 64 + t] = part[0][t] + part[1][t] + part[2][t] + part[3][t];
}

extern "C" void kernel_launch(void* const* d_in, const int* in_sizes, int n_in,
                              void* d_out, int out_size, void* d_ws, size_t ws_size,
                              hipStream_t stream) {
    const int* nodes = (const int*)d_in[0];
    const int* neigh = (const int*)d_in[1];
    const int* segs  = (const int*)d_in[2];
    const float* u2e = (const float*)d_in[3];
    const float* w1  = (const float*)d_in[4];
    const float* b1  = (const float*)d_in[5];
    const float* w2  = (const float*)d_in[6];
    const float* b2  = (const float*)d_in[7];
    const float* w3  = (const float*)d_in[8];
    const float* b3  = (const float*)d_in[9];
    const int N = in_sizes[0];
    const int E = in_sizes[1];
    const long VD = in_sizes[3];

    char* ws = (char*)d_ws;
    size_t off = 0;
    auto alloc = [&](size_t bytes) { char* p = ws + off; off = (off + bytes + 255) & ~(size_t)255; return p; };
    float* logits = (float*)alloc((size_t)E * 4);
    int* seg_off = (int*)alloc((size_t)(N + 1) * 4);
    unsigned short* w1t = (unsigned short*)alloc(128 * 64 * 2);
    unsigned short* w2t = (unsigned short*)alloc(64 * 64 * 2);
    unsigned short* u2ebf = (unsigned short*)alloc((size_t)VD * 2);
    size_t need_bf = off;
    float* z = (float*)alloc((size_t)N * 64 * 4);
    size_t need_z = off;

    float* out = (float*)d_out;

    prep_k<<<1, 256, 0, stream>>>(w1, w2, w1t, w2t);
    bounds_k<<<(N + 256) / 256, 256, 0, stream>>>(segs, seg_off, N, E);

    const int waves1 = (E + 15) / 16;
    const int blocks1 = (waves1 + 3) / 4;

    if (ws_size >= need_z) {
        long n8 = VD / 8;
        convert_k<<<(int)((n8 + 255) / 256), 256, 0, stream>>>(u2e, u2ebf, n8);
        const int zwaves = (N + 15) / 16;
        z_k<<<(zwaves + 3) / 4, 256, 0, stream>>>(nodes, u2ebf, w1t, b1, z, N);
        logits_k<<<blocks1, 256, 0, stream>>>(neigh, segs, u2ebf, z, w1t, w2t,
                                              b2, w3, b3, logits, E);
        agg_k<<<N, 256, 0, stream>>>(seg_off, neigh, u2ebf, logits, out, N);
    } else if (ws_size >= need_bf) {
        long n8 = VD / 8;
        convert_k<<<(int)((n8 + 255) / 256), 256, 0, stream>>>(u2e, u2ebf, n8);
        logits_fb_k<<<blocks1, 256, 0, stream>>>(nodes, neigh, segs, u2e, w1t, w2t,
                                                 b1, b2, w3, b3, logits, E);
        agg_k<<<N, 256, 0, stream>>>(seg_off, neigh, u2ebf, logits, out, N);
    } else {
        logits_fb_k<<<blocks1, 256, 0, stream>>>(nodes, neigh, segs, u2e, w1t, w2t,
                                                 b1, b2, w3, b3, logits, E);
        agg_fb_k<<<N, 256, 0, stream>>>(seg_off, neigh, u2e, logits, out, N);
    }
}

// Round 5
// 220.979 us; speedup vs baseline: 1.4971x; 1.0996x over previous
//
#include <hip/hip_runtime.h>
#include <hip/hip_bf16.h>

typedef __attribute__((ext_vector_type(8))) short bf16x8;
typedef __attribute__((ext_vector_type(4))) float f32x4;

__device__ __forceinline__ float bf2fs(short s) {
    return __uint_as_float(((unsigned)(unsigned short)s) << 16);
}
__device__ __forceinline__ unsigned short f2bf(float f) {
    unsigned x = __float_as_uint(f);
    unsigned r = (x + 0x7FFF + ((x >> 16) & 1)) >> 16;   // RNE
    return (unsigned short)r;
}
__device__ __forceinline__ bf16x8 cvt8(const float* __restrict__ p) {
    bf16x8 r;
#pragma unroll
    for (int j = 0; j < 8; ++j) r[j] = (short)f2bf(p[j]);
    return r;
}

// ---------------- kernel 0a: weight prep (bf16 transpose to n-major) ------------
__global__ void prep_k(const float* __restrict__ w1,
                       const float* __restrict__ w2,
                       unsigned short* __restrict__ w1t,
                       unsigned short* __restrict__ w2t) {
    int t = threadIdx.x;
    for (int i = t; i < 128 * 64; i += 256) {
        int k = i >> 6, n = i & 63;
        w1t[n * 128 + k] = f2bf(w1[i]);
    }
    for (int i = t; i < 64 * 64; i += 256) {
        int k = i >> 6, n = i & 63;
        w2t[n * 64 + k] = f2bf(w2[i]);
    }
}

// ---------------- kernel 0b: u2e f32 -> bf16 (streaming) ------------------------
__global__ void convert_k(const float* __restrict__ src,
                          unsigned short* __restrict__ dst, long n8) {
    long t = (long)blockIdx.x * blockDim.x + threadIdx.x;
    if (t >= n8) return;
    *(bf16x8*)(dst + t * 8) = cvt8(src + t * 8);
}

// ---------------- kernel 0c: segment offsets via parallel binary search ---------
__global__ void bounds_k(const int* __restrict__ segs, int* __restrict__ seg_off,
                         int N, int E) {
    int t = blockIdx.x * blockDim.x + threadIdx.x;
    if (t > N) return;
    int l = 0, r = E;
    while (l < r) { int mid = (l + r) >> 1; if (segs[mid] < t) l = mid + 1; else r = mid; }
    seg_off[t] = l;
}

// ---------------- kernel 0d: Y[v] = u2e[v] @ W1_top  (bf16 out) -----------------
// One wave per 16 rows; rows coalesced (row = base + m15). K=64 (W1 rows 0..63).
template <bool BF>
__launch_bounds__(256)
__global__ void y_k(const unsigned short* __restrict__ u2ebf,
                    const float* __restrict__ u2e,
                    const unsigned short* __restrict__ w1t,
                    unsigned short* __restrict__ Y, int V) {
    const int wid = threadIdx.x >> 6;
    const int lane = threadIdx.x & 63;
    const int q = lane >> 4;
    const int m15 = lane & 15;
    const int wbase = (blockIdx.x * 4 + wid) * 16;
    if (wbase >= V) return;
    int row = min(wbase + m15, V - 1);

    bf16x8 a0, a1;
    if constexpr (BF) {
        const unsigned short* p = u2ebf + (long)row * 64;
        a0 = *(const bf16x8*)(p + q * 8);
        a1 = *(const bf16x8*)(p + 32 + q * 8);
    } else {
        const float* p = u2e + (long)row * 64;
        a0 = cvt8(p + q * 8);
        a1 = cvt8(p + 32 + q * 8);
    }

    f32x4 acc[4];
#pragma unroll
    for (int b = 0; b < 4; ++b) {
        acc[b] = (f32x4){0.f, 0.f, 0.f, 0.f};
        const bf16x8* wrow = (const bf16x8*)(w1t + (b * 16 + m15) * 128);
        acc[b] = __builtin_amdgcn_mfma_f32_16x16x32_bf16(a0, wrow[0 + q], acc[b], 0, 0, 0);
        acc[b] = __builtin_amdgcn_mfma_f32_16x16x32_bf16(a1, wrow[4 + q], acc[b], 0, 0, 0);
    }
#pragma unroll
    for (int b = 0; b < 4; ++b)
#pragma unroll
        for (int r = 0; r < 4; ++r) {
            int rr = wbase + q * 4 + r;
            if (rr < V) Y[(long)rr * 64 + b * 16 + m15] = f2bf(acc[b][r]);
        }
}

// ---------------- kernel 0e: z[n] = u2e[nodes[n]] @ W1_bot + b1 (bf16 out) ------
template <bool BF>
__launch_bounds__(256)
__global__ void z_k(const int* __restrict__ nodes,
                    const unsigned short* __restrict__ u2ebf,
                    const float* __restrict__ u2e,
                    const unsigned short* __restrict__ w1t,
                    const float* __restrict__ b1f,
                    unsigned short* __restrict__ z, int N) {
    const int wid = threadIdx.x >> 6;
    const int lane = threadIdx.x & 63;
    const int q = lane >> 4;
    const int m15 = lane & 15;
    const int wbase = (blockIdx.x * 4 + wid) * 16;
    if (wbase >= N) return;
    int nd = nodes[min(wbase + m15, N - 1)];

    bf16x8 a0, a1;
    if constexpr (BF) {
        const unsigned short* p = u2ebf + (long)nd * 64;
        a0 = *(const bf16x8*)(p + q * 8);
        a1 = *(const bf16x8*)(p + 32 + q * 8);
    } else {
        const float* p = u2e + (long)nd * 64;
        a0 = cvt8(p + q * 8);
        a1 = cvt8(p + 32 + q * 8);
    }

    f32x4 acc[4];
#pragma unroll
    for (int b = 0; b < 4; ++b) {
        float bv = b1f[b * 16 + m15];
        acc[b] = (f32x4){bv, bv, bv, bv};
        const bf16x8* wrow = (const bf16x8*)(w1t + (b * 16 + m15) * 128);
        acc[b] = __builtin_amdgcn_mfma_f32_16x16x32_bf16(a0, wrow[8 + q], acc[b], 0, 0, 0);
        acc[b] = __builtin_amdgcn_mfma_f32_16x16x32_bf16(a1, wrow[12 + q], acc[b], 0, 0, 0);
    }
#pragma unroll
    for (int b = 0; b < 4; ++b)
#pragma unroll
        for (int r = 0; r < 4; ++r) {
            int rr = wbase + q * 4 + r;
            if (rr < N) z[(long)rr * 64 + b * 16 + m15] = f2bf(acc[b][r]);
        }
}

// ---------------- kernel 1: per-edge MLP layer2+3 -> ex = exp(logit) ------------
// h1 built in-register: h1 = relu(z[seg[e]] + Y[neigh[e]]) directly in A-layout.
// No layer-1 MFMA, no LDS. Softmax shift dropped (logits ~1e-2; exp safe in f32).
__launch_bounds__(256)
__global__ void logits_k(const int* __restrict__ neigh,
                         const int* __restrict__ segs,
                         const unsigned short* __restrict__ Y,
                         const unsigned short* __restrict__ z,
                         const unsigned short* __restrict__ w2t,
                         const float* __restrict__ b2f,
                         const float* __restrict__ w3f, const float* __restrict__ b3f,
                         float* __restrict__ ex, int E) {
    const int lane = threadIdx.x & 63;
    const int wid = threadIdx.x >> 6;
    const int q = lane >> 4;
    const int m15 = lane & 15;
    const long base = ((long)blockIdx.x * 4 + wid) * 16;

    long ee0 = base + m15;
    int e = (int)(ee0 < E ? ee0 : (long)E - 1);
    int vi = neigh[e];
    int sg = segs[e];
    const unsigned short* yr = Y + (long)vi * 64;
    const unsigned short* zr = z + (long)sg * 64;

    bf16x8 y0 = *(const bf16x8*)(yr + q * 8);
    bf16x8 y1 = *(const bf16x8*)(yr + 32 + q * 8);
    bf16x8 z0 = *(const bf16x8*)(zr + q * 8);
    bf16x8 z1 = *(const bf16x8*)(zr + 32 + q * 8);

    bf16x8 h0, h1;
#pragma unroll
    for (int j = 0; j < 8; ++j) {
        h0[j] = (short)f2bf(fmaxf(bf2fs(y0[j]) + bf2fs(z0[j]), 0.0f));
        h1[j] = (short)f2bf(fmaxf(bf2fs(y1[j]) + bf2fs(z1[j]), 0.0f));
    }

    // ---- layer 2: h2 = relu(h1 @ W2 + b2), K=64
    f32x4 acc2[4];
#pragma unroll
    for (int b = 0; b < 4; ++b) {
        float bv = b2f[b * 16 + m15];
        acc2[b] = (f32x4){bv, bv, bv, bv};
        const bf16x8* wrow = (const bf16x8*)(w2t + (b * 16 + m15) * 64);
        acc2[b] = __builtin_amdgcn_mfma_f32_16x16x32_bf16(h0, wrow[0 + q], acc2[b], 0, 0, 0);
        acc2[b] = __builtin_amdgcn_mfma_f32_16x16x32_bf16(h1, wrow[4 + q], acc2[b], 0, 0, 0);
    }

    // ---- layer 3 + exp
    float b3v = b3f[0];
#pragma unroll
    for (int r = 0; r < 4; ++r) {
        float v = 0.0f;
#pragma unroll
        for (int b = 0; b < 4; ++b) v += fmaxf(acc2[b][r], 0.0f) * w3f[b * 16 + m15];
        v += __shfl_xor(v, 1);
        v += __shfl_xor(v, 2);
        v += __shfl_xor(v, 4);
        v += __shfl_xor(v, 8);
        long ee = base + q * 4 + r;
        if (m15 == r && ee < E) ex[ee] = __expf(v + b3v);
    }
}

// ---------------- kernel 2: single-phase weighted segment sum -------------------
// One block per node; 8 edge slots (half-wave x 2 bf16 channels per dword).
// No max pass, no exp, no staging; normalize by sum(ex) at the end.
template <bool BF>
__launch_bounds__(256)
__global__ void agg_k(const int* __restrict__ seg_off,
                      const int* __restrict__ neigh,
                      const unsigned short* __restrict__ u2ebf,
                      const float* __restrict__ u2e,
                      const float* __restrict__ ex,
                      float* __restrict__ out, int N) {
    __shared__ float part[4][64];
    __shared__ float redbuf[4];

    const int n = blockIdx.x;
    const int t = threadIdx.x;
    const int wid = t >> 6;
    const int lane = t & 63;
    const int lo = seg_off[n];
    const int hi = seg_off[n + 1];

    const int slot = t >> 5;        // 0..7
    const int c = lane & 31;        // channel pair index

    float ax = 0.0f, ay = 0.0f, s = 0.0f;
    for (int e = lo + slot; e < hi; e += 8) {
        float a = ex[e];            // half-wave broadcast
        int vi = neigh[e];          // half-wave broadcast
        if constexpr (BF) {
            unsigned v = *(const unsigned*)(u2ebf + (long)vi * 64 + c * 2);
            ax = fmaf(a, __uint_as_float(v << 16), ax);
            ay = fmaf(a, __uint_as_float(v & 0xFFFF0000u), ay);
        } else {
            float2 v = *(const float2*)(u2e + (long)vi * 64 + c * 2);
            ax = fmaf(a, v.x, ax);
            ay = fmaf(a, v.y, ay);
        }
        s += a;
    }
    // fold the two half-wave slots (channels align)
    ax += __shfl_xor(ax, 32);
    ay += __shfl_xor(ay, 32);
    if (lane < 32) {
        part[wid][c * 2] = ax;
        part[wid][c * 2 + 1] = ay;
    }
    // sum(ex): one representative lane per half-wave, then wave reduce
    s = ((lane & 31) == 0) ? s : 0.0f;
    s += __shfl_xor(s, 32);
    s += __shfl_xor(s, 16);
    s += __shfl_xor(s, 8);
    s += __shfl_xor(s, 4);
    s += __shfl_xor(s, 2);
    s += __shfl_xor(s, 1);
    if (lane == 0) redbuf[wid] = s;
    __syncthreads();
    if (t < 64) {
        float stot = redbuf[0] + redbuf[1] + redbuf[2] + redbuf[3];
        float inv = 1.0f / fmaxf(stot, 1e-9f);
        out[(long)n * 64 + t] =
            (part[0][t] + part[1][t] + part[2][t] + part[3][t]) * inv;
    }
}

// ---------------- tier-3 fallback (tiny ws): round-3 style ---------------------
__launch_bounds__(256)
__global__ void logits_fb_k(const int* __restrict__ nodes,
                            const int* __restrict__ neigh,
                            const int* __restrict__ segs,
                            const float* __restrict__ u2e,
                            const unsigned short* __restrict__ w1t,
                            const unsigned short* __restrict__ w2t,
                            const float* __restrict__ b1f, const float* __restrict__ b2f,
                            const float* __restrict__ w3f, const float* __restrict__ b3f,
                            float* __restrict__ ex, int E) {
    __shared__ __align__(16) unsigned short h1buf[4][16 * 72];
    const int wid = threadIdx.x >> 6;
    const int lane = threadIdx.x & 63;
    const int q = lane >> 4;
    const int m15 = lane & 15;
    const long base = ((long)blockIdx.x * 4 + wid) * 16;
    long ee0 = base + m15;
    int e = (int)(ee0 < E ? ee0 : (long)E - 1);
    int ni = neigh[e];
    int ctr = nodes[segs[e]];
    const float* eu = u2e + (long)ni * 64;
    const float* ur = u2e + (long)ctr * 64;
    bf16x8 a0 = cvt8(eu + q * 8), a1 = cvt8(eu + 32 + q * 8);
    bf16x8 a2 = cvt8(ur + q * 8), a3 = cvt8(ur + 32 + q * 8);
    f32x4 acc[4];
#pragma unroll
    for (int b = 0; b < 4; ++b) {
        float bv = b1f[b * 16 + m15];
        acc[b] = (f32x4){bv, bv, bv, bv};
        const bf16x8* wrow = (const bf16x8*)(w1t + (b * 16 + m15) * 128);
        acc[b] = __builtin_amdgcn_mfma_f32_16x16x32_bf16(a0, wrow[0 + q], acc[b], 0, 0, 0);
        acc[b] = __builtin_amdgcn_mfma_f32_16x16x32_bf16(a1, wrow[4 + q], acc[b], 0, 0, 0);
        acc[b] = __builtin_amdgcn_mfma_f32_16x16x32_bf16(a2, wrow[8 + q], acc[b], 0, 0, 0);
        acc[b] = __builtin_amdgcn_mfma_f32_16x16x32_bf16(a3, wrow[12 + q], acc[b], 0, 0, 0);
    }
#pragma unroll
    for (int b = 0; b < 4; ++b)
#pragma unroll
        for (int r = 0; r < 4; ++r)
            h1buf[wid][(q * 4 + r) * 72 + b * 16 + m15] = f2bf(fmaxf(acc[b][r], 0.0f));
    const unsigned short* hrow = &h1buf[wid][m15 * 72];
    bf16x8 h0 = *(const bf16x8*)(hrow + q * 8);
    bf16x8 h1 = *(const bf16x8*)(hrow + 32 + q * 8);
    f32x4 acc2[4];
#pragma unroll
    for (int b = 0; b < 4; ++b) {
        float bv = b2f[b * 16 + m15];
        acc2[b] = (f32x4){bv, bv, bv, bv};
        const bf16x8* wrow = (const bf16x8*)(w2t + (b * 16 + m15) * 64);
        acc2[b] = __builtin_amdgcn_mfma_f32_16x16x32_bf16(h0, wrow[0 + q], acc2[b], 0, 0, 0);
        acc2[b] = __builtin_amdgcn_mfma_f32_16x16x32_bf16(h1, wrow[4 + q], acc2[b], 0, 0, 0);
    }
    float b3v = b3f[0];
#pragma unroll
    for (int r = 0; r < 4; ++r) {
        float v = 0.0f;
#pragma unroll
        for (int b = 0; b < 4; ++b) v += fmaxf(acc2[b][r], 0.0f) * w3f[b * 16 + m15];
        v += __shfl_xor(v, 1);
        v += __shfl_xor(v, 2);
        v += __shfl_xor(v, 4);
        v += __shfl_xor(v, 8);
        long ee = base + q * 4 + r;
        if (m15 == r && ee < E) ex[ee] = __expf(v + b3v);
    }
}

extern "C" void kernel_launch(void* const* d_in, const int* in_sizes, int n_in,
                              void* d_out, int out_size, void* d_ws, size_t ws_size,
                              hipStream_t stream) {
    const int* nodes = (const int*)d_in[0];
    const int* neigh = (const int*)d_in[1];
    const int* segs  = (const int*)d_in[2];
    const float* u2e = (const float*)d_in[3];
    const float* w1  = (const float*)d_in[4];
    const float* b1  = (const float*)d_in[5];
    const float* w2  = (const float*)d_in[6];
    const float* b2  = (const float*)d_in[7];
    const float* w3  = (const float*)d_in[8];
    const float* b3  = (const float*)d_in[9];
    const int N = in_sizes[0];
    const int E = in_sizes[1];
    const long VD = in_sizes[3];
    const int V = (int)(VD / 64);

    char* ws = (char*)d_ws;
    size_t off = 0;
    auto alloc = [&](size_t bytes) { char* p = ws + off; off = (off + bytes + 255) & ~(size_t)255; return p; };
    float* ex = (float*)alloc((size_t)E * 4);
    int* seg_off = (int*)alloc((size_t)(N + 1) * 4);
    unsigned short* w1t = (unsigned short*)alloc(128 * 64 * 2);
    unsigned short* w2t = (unsigned short*)alloc(64 * 64 * 2);
    size_t need_min = off;
    unsigned short* Y = (unsigned short*)alloc((size_t)VD * 2);        // V x 64 bf16
    unsigned short* zb = (unsigned short*)alloc((size_t)N * 64 * 2);   // N x 64 bf16
    size_t need_t2 = off;
    unsigned short* u2ebf = (unsigned short*)alloc((size_t)VD * 2);
    size_t need_t1 = off;

    float* out = (float*)d_out;

    prep_k<<<1, 256, 0, stream>>>(w1, w2, w1t, w2t);
    bounds_k<<<(N + 256) / 256, 256, 0, stream>>>(segs, seg_off, N, E);

    const int blocks1 = ((E + 15) / 16 + 3) / 4;
    const int yblocks = ((V + 15) / 16 + 3) / 4;
    const int zblocks = ((N + 15) / 16 + 3) / 4;

    if (ws_size >= need_t1) {
        long n8 = VD / 8;
        convert_k<<<(int)((n8 + 255) / 256), 256, 0, stream>>>(u2e, u2ebf, n8);
        y_k<true><<<yblocks, 256, 0, stream>>>(u2ebf, nullptr, w1t, Y, V);
        z_k<true><<<zblocks, 256, 0, stream>>>(nodes, u2ebf, nullptr, w1t, b1, zb, N);
        logits_k<<<blocks1, 256, 0, stream>>>(neigh, segs, Y, zb, w2t, b2, w3, b3, ex, E);
        agg_k<true><<<N, 256, 0, stream>>>(seg_off, neigh, u2ebf, nullptr, ex, out, N);
    } else if (ws_size >= need_t2) {
        y_k<false><<<yblocks, 256, 0, stream>>>(nullptr, u2e, w1t, Y, V);
        z_k<false><<<zblocks, 256, 0, stream>>>(nodes, nullptr, u2e, w1t, b1, zb, N);
        logits_k<<<blocks1, 256, 0, stream>>>(neigh, segs, Y, zb, w2t, b2, w3, b3, ex, E);
        agg_k<false><<<N, 256, 0, stream>>>(seg_off, neigh, nullptr, u2e, ex, out, N);
    } else {
        logits_fb_k<<<blocks1, 256, 0, stream>>>(nodes, neigh, segs, u2e, w1t, w2t,
                                                 b1, b2, w3, b3, ex, E);
        agg_k<false><<<N, 256, 0, stream>>>(seg_off, neigh, nullptr, u2e, ex, out, N);
    }
}